// Round 3
// baseline (56.954 us; speedup 1.0000x reference)
//
#include <hip/hip_runtime.h>
#include <math.h>

// native 4-float vector for nontemporal builtins (HIP float4 is a class type)
typedef float vfloat4 __attribute__((ext_vector_type(4)));

// ---------------- workspace layout (float offsets) ----------------
// W_PART : 64 * 512         = 32768   (per-block partial column sums of conv_w)
// WSUM   : 512                         (sum_o conv_w[o][c])
// P2     : 32 * 8 * 196     = 50176   (per (n, c-chunk) partial small masks)
// MASK   : 32 * 3136        = 100352  (final premultiplied mask v*a+b, fp32)
#define W_PART_OFF 0
#define WSUM_OFF   32768
#define P2_OFF     33280
#define MASK_OFF   83456
// total: 183808 floats = ~735 KB of d_ws

// Sum conv_w over output channels (rows). conv_w is [256][512].
// 64 blocks x 256 threads: block b reduces rows [4b, 4b+4) into partials.
__global__ void k_wsum_part(const float* __restrict__ conv_w, float* __restrict__ ws) {
    int b = blockIdx.x;        // 0..63
    int t = threadIdx.x;       // 0..255
    float a0 = 0.f, a1 = 0.f;
    int o0 = b * 4;
#pragma unroll
    for (int o = o0; o < o0 + 4; ++o) {
        a0 += conv_w[o * 512 + t];
        a1 += conv_w[o * 512 + t + 256];
    }
    ws[W_PART_OFF + b * 512 + t]       = a0;
    ws[W_PART_OFF + b * 512 + t + 256] = a1;
}

// 2 blocks x 256 threads: wsum[c] = sum over the 64 partials.
__global__ void k_wsum_final(float* __restrict__ ws) {
    int c = blockIdx.x * 256 + threadIdx.x;
    float a = 0.f;
#pragma unroll 8
    for (int k = 0; k < 64; ++k) a += ws[W_PART_OFF + k * 512 + c];
    ws[WSUM_OFF + c] = a;
}

// mask_small partials: grid (32 n, 8 chunks) x 256 threads.
// Each block: dot 64 channels of emb[n,:,14,14] with wsum chunk.
__global__ void k_mask_small(const float* __restrict__ emb, float* __restrict__ ws) {
    __shared__ float wl[64];
    int n  = blockIdx.x;   // 0..31
    int cc = blockIdx.y;   // 0..7
    int t  = threadIdx.x;  // 0..255
    if (t < 64) wl[t] = ws[WSUM_OFF + cc * 64 + t];
    __syncthreads();
    if (t < 196) {
        const float* base = emb + (size_t)(n * 512 + cc * 64) * 196 + t;
        float acc = 0.f;
#pragma unroll 8
        for (int c = 0; c < 64; ++c) acc += base[c * 196] * wl[c];
        ws[P2_OFF + (n * 8 + cc) * 196 + t] = acc;
    }
}

// Per-sample: combine partials -> 14x14 in LDS, bilinear upsample to 56x56
// (half-pixel, clamped == jax renormalized triangle kernel for scale 4),
// block min/max reduce, then store premultiplied mask m' = v*a + b with
// a = weight/(mx-mn), b = 1 - mn*a.  (mean-factor and conv_b drop out of the
// min-max norm; the reference's second _minmax_norm is exactly identity.)
__global__ void k_upsample(const float* __restrict__ wgt_p, float* __restrict__ ws) {
    __shared__ float sm[196];
    __shared__ float rmin[256], rmax[256];
    int n = blockIdx.x;   // 0..31
    int t = threadIdx.x;  // 0..255

    if (t < 196) {
        float a = 0.f;
#pragma unroll
        for (int k = 0; k < 8; ++k) a += ws[P2_OFF + (n * 8 + k) * 196 + t];
        sm[t] = a;
    }
    __syncthreads();

    float vmin = INFINITY, vmax = -INFINITY;
    for (int p = t; p < 3136; p += 256) {
        int h = p / 56, w = p % 56;
        float sy = (h + 0.5f) * 0.25f - 0.5f;
        float sx = (w + 0.5f) * 0.25f - 0.5f;
        int y0 = (int)floorf(sy); float fy = sy - (float)y0;
        int x0 = (int)floorf(sx); float fx = sx - (float)x0;
        int y1 = min(y0 + 1, 13); y0 = max(y0, 0);
        int x1 = min(x0 + 1, 13); x0 = max(x0, 0);
        float v00 = sm[y0 * 14 + x0], v01 = sm[y0 * 14 + x1];
        float v10 = sm[y1 * 14 + x0], v11 = sm[y1 * 14 + x1];
        float v = (1.f - fy) * ((1.f - fx) * v00 + fx * v01)
                +        fy  * ((1.f - fx) * v10 + fx * v11);
        vmin = fminf(vmin, v);
        vmax = fmaxf(vmax, v);
    }
    rmin[t] = vmin; rmax[t] = vmax;
    __syncthreads();
    for (int s = 128; s > 0; s >>= 1) {
        if (t < s) {
            rmin[t] = fminf(rmin[t], rmin[t + s]);
            rmax[t] = fmaxf(rmax[t], rmax[t + s]);
        }
        __syncthreads();
    }
    float mn = rmin[0], mx = rmax[0];
    float a = wgt_p[0] / (mx - mn);
    float b = 1.f - mn * a;

    // recompute (trivial) and store premultiplied mask
    for (int p = t; p < 3136; p += 256) {
        int h = p / 56, w = p % 56;
        float sy = (h + 0.5f) * 0.25f - 0.5f;
        float sx = (w + 0.5f) * 0.25f - 0.5f;
        int y0 = (int)floorf(sy); float fy = sy - (float)y0;
        int x0 = (int)floorf(sx); float fx = sx - (float)x0;
        int y1 = min(y0 + 1, 13); y0 = max(y0, 0);
        int x1 = min(x0 + 1, 13); x0 = max(x0, 0);
        float v00 = sm[y0 * 14 + x0], v01 = sm[y0 * 14 + x1];
        float v10 = sm[y1 * 14 + x0], v11 = sm[y1 * 14 + x1];
        float v = (1.f - fy) * ((1.f - fx) * v00 + fx * v01)
                +        fy  * ((1.f - fx) * v10 + fx * v11);
        ws[MASK_OFF + n * 3136 + p] = v * a + b;
    }
}

// Big elementwise pass: out = sigmoid(x) * m'.
// 49 blocks per sample; each block owns 4096 consecutive float4 of one sample.
// Mask (784 float4 per sample) staged in LDS once -> only ONE VMEM load per
// iter; mask phase tracked incrementally (no div/mod in loop).
// Non-temporal stores keep the 100 MB output stream out of L2/L3 so the
// input stays Infinity-Cache-resident across graph replays.
__global__ void __launch_bounds__(256) k_final(const float4* __restrict__ x4,
                                               const float* __restrict__ ws,
                                               float4* __restrict__ out4) {
    __shared__ float4 mlds[784];
    const int bid = blockIdx.x;
    const int t   = threadIdx.x;
    const int n   = bid / 49;          // sample
    const int s   = bid - n * 49;      // segment within sample
    const float4* m4 = (const float4*)(ws + MASK_OFF) + n * 784;
    for (int k = t; k < 784; k += 256) mlds[k] = m4[k];
    __syncthreads();

    const long base = (long)n * 200704 + (long)s * 4096;
    const float4* xp = x4 + base;
    vfloat4*      op = (vfloat4*)(out4 + base);
    // mask float4-phase of element (base + t):  4096 % 784 == 176
    int p = (s * 176 + t) % 784;

#pragma unroll 8
    for (int i = 0; i < 16; ++i) {
        float4 x = xp[i * 256 + t];
        float4 m = mlds[p];
        vfloat4 o;
        o.x = m.x * __builtin_amdgcn_rcpf(1.f + __expf(-x.x));
        o.y = m.y * __builtin_amdgcn_rcpf(1.f + __expf(-x.y));
        o.z = m.z * __builtin_amdgcn_rcpf(1.f + __expf(-x.z));
        o.w = m.w * __builtin_amdgcn_rcpf(1.f + __expf(-x.w));
        __builtin_nontemporal_store(o, &op[i * 256 + t]);
        p += 256;
        if (p >= 784) p -= 784;
    }
}

extern "C" void kernel_launch(void* const* d_in, const int* in_sizes, int n_in,
                              void* d_out, int out_size, void* d_ws, size_t ws_size,
                              hipStream_t stream) {
    const float* main_in = (const float*)d_in[0];  // [32,256,56,56]
    const float* emb_in  = (const float*)d_in[1];  // [32,512,14,14]
    const float* conv_w  = (const float*)d_in[2];  // [256,512]
    // d_in[3] = conv_b : provably dead (shift-invariant under min-max norm)
    const float* weight  = (const float*)d_in[4];  // scalar

    float* ws   = (float*)d_ws;
    float4* out = (float4*)d_out;

    k_wsum_part <<<64,          256, 0, stream>>>(conv_w, ws);
    k_wsum_final<<<2,           256, 0, stream>>>(ws);
    k_mask_small<<<dim3(32, 8), 256, 0, stream>>>(emb_in, ws);
    k_upsample  <<<32,          256, 0, stream>>>(weight, ws);
    k_final     <<<1568,        256, 0, stream>>>((const float4*)main_in, ws, out);
}

// Round 4
// 48.552 us; speedup vs baseline: 1.1731x; 1.1731x over previous
//
#include <hip/hip_runtime.h>
#include <math.h>

// ---------------- workspace layout (float offsets) ----------------
// P2   : 32 * 8 * 196 = 50176   (per (n, c-chunk) partial small masks)
// MASK : 32 * 3136    = 100352  (final premultiplied mask v*a+b, fp32)
#define P2_OFF     33280
#define MASK_OFF   83456

// Fused: per-block column-sum chunk of conv_w + channel dot at 14x14.
// grid (32 n, 8 cc) x 256 threads.
// wsum[c] = sum_o conv_w[o][c]; the 1x1-conv + channel-mean commute, and the
// 1/C factor + conv_b drop out of the min-max norm entirely.
__global__ void k_mask_small(const float* __restrict__ emb,
                             const float* __restrict__ conv_w,
                             float* __restrict__ ws) {
    __shared__ float wpart[256];
    __shared__ float wl[64];
    int n  = blockIdx.x;   // 0..31
    int cc = blockIdx.y;   // 0..7
    int t  = threadIdx.x;  // 0..255

    // column partial sums: thread (rg,col) sums 64 rows of column cc*64+col
    int col = t & 63, rg = t >> 6;
    float a = 0.f;
    const float* wp = conv_w + (rg * 64) * 512 + cc * 64 + col;
#pragma unroll 8
    for (int k = 0; k < 64; ++k) a += wp[k * 512];
    wpart[t] = a;
    __syncthreads();
    if (t < 64) wl[t] = wpart[t] + wpart[t + 64] + wpart[t + 128] + wpart[t + 192];
    __syncthreads();

    if (t < 196) {
        const float* base = emb + (size_t)(n * 512 + cc * 64) * 196 + t;
        float acc = 0.f;
#pragma unroll 8
        for (int c = 0; c < 64; ++c) acc += base[c * 196] * wl[c];
        ws[P2_OFF + (n * 8 + cc) * 196 + t] = acc;
    }
}

// Per-sample: combine partials -> 14x14 in LDS, bilinear upsample to 56x56
// (half-pixel, clamped == jax renormalized triangle kernel for scale 4),
// block min/max reduce, then store premultiplied mask m' = v*a + b with
// a = weight/(mx-mn), b = 1 - mn*a.  (The reference's second _minmax_norm is
// exactly identity after the first.)
__global__ void k_upsample(const float* __restrict__ wgt_p, float* __restrict__ ws) {
    __shared__ float sm[196];
    __shared__ float rmin[256], rmax[256];
    int n = blockIdx.x;   // 0..31
    int t = threadIdx.x;  // 0..255

    if (t < 196) {
        float a = 0.f;
#pragma unroll
        for (int k = 0; k < 8; ++k) a += ws[P2_OFF + (n * 8 + k) * 196 + t];
        sm[t] = a;
    }
    __syncthreads();

    float vmin = INFINITY, vmax = -INFINITY;
    for (int p = t; p < 3136; p += 256) {
        int h = p / 56, w = p % 56;
        float sy = (h + 0.5f) * 0.25f - 0.5f;
        float sx = (w + 0.5f) * 0.25f - 0.5f;
        int y0 = (int)floorf(sy); float fy = sy - (float)y0;
        int x0 = (int)floorf(sx); float fx = sx - (float)x0;
        int y1 = min(y0 + 1, 13); y0 = max(y0, 0);
        int x1 = min(x0 + 1, 13); x0 = max(x0, 0);
        float v00 = sm[y0 * 14 + x0], v01 = sm[y0 * 14 + x1];
        float v10 = sm[y1 * 14 + x0], v11 = sm[y1 * 14 + x1];
        float v = (1.f - fy) * ((1.f - fx) * v00 + fx * v01)
                +        fy  * ((1.f - fx) * v10 + fx * v11);
        vmin = fminf(vmin, v);
        vmax = fmaxf(vmax, v);
    }
    rmin[t] = vmin; rmax[t] = vmax;
    __syncthreads();
    for (int s = 128; s > 0; s >>= 1) {
        if (t < s) {
            rmin[t] = fminf(rmin[t], rmin[t + s]);
            rmax[t] = fmaxf(rmax[t], rmax[t + s]);
        }
        __syncthreads();
    }
    float mn = rmin[0], mx = rmax[0];
    float a = wgt_p[0] / (mx - mn);
    float b = 1.f - mn * a;

    for (int p = t; p < 3136; p += 256) {
        int h = p / 56, w = p % 56;
        float sy = (h + 0.5f) * 0.25f - 0.5f;
        float sx = (w + 0.5f) * 0.25f - 0.5f;
        int y0 = (int)floorf(sy); float fy = sy - (float)y0;
        int x0 = (int)floorf(sx); float fx = sx - (float)x0;
        int y1 = min(y0 + 1, 13); y0 = max(y0, 0);
        int x1 = min(x0 + 1, 13); x0 = max(x0, 0);
        float v00 = sm[y0 * 14 + x0], v01 = sm[y0 * 14 + x1];
        float v10 = sm[y1 * 14 + x0], v11 = sm[y1 * 14 + x1];
        float v = (1.f - fy) * ((1.f - fx) * v00 + fx * v01)
                +        fy  * ((1.f - fx) * v10 + fx * v11);
        ws[MASK_OFF + n * 3136 + p] = v * a + b;
    }
}

// Big elementwise pass: out = sigmoid(x) * m'.
// grid (196 seg, 32 n) x 256 threads; each block owns 1024 contiguous float4
// of one sample (4 iters). ~8 resident blocks/CU at 100% wave occupancy,
// perfectly balanced (6272 blocks). One %784 at entry; loop indices are
// compile-time unrolled + independent so all loads issue together.
// Mask read straight from global: 400 KB, L2-hot.
__global__ void __launch_bounds__(256) k_final(const float4* __restrict__ x4,
                                               const float* __restrict__ ws,
                                               float4* __restrict__ out4) {
    const int t = threadIdx.x;
    const int s = blockIdx.x;          // 0..195 segment
    const int n = blockIdx.y;          // 0..31  sample
    const float4* m4 = (const float4*)(ws + MASK_OFF) + n * 784;

    const long base = (long)n * 200704 + (long)s * 1024;
    const float4* xp = x4   + base;
    float4*       op = out4 + base;

    // phase of float4 (base + t) within the 784-float4 mask plane:
    // 1024 % 784 == 240
    const int p0 = (s * 240 + t) % 784;

#pragma unroll
    for (int i = 0; i < 4; ++i) {
        int q = p0 + i * 256;
        if (q >= 784) q -= 784;        // p0+768 < 1552 < 2*784: one subtract
        float4 x = xp[i * 256 + t];
        float4 m = m4[q];
        float4 o;
        o.x = m.x * __builtin_amdgcn_rcpf(1.f + __expf(-x.x));
        o.y = m.y * __builtin_amdgcn_rcpf(1.f + __expf(-x.y));
        o.z = m.z * __builtin_amdgcn_rcpf(1.f + __expf(-x.z));
        o.w = m.w * __builtin_amdgcn_rcpf(1.f + __expf(-x.w));
        op[i * 256 + t] = o;
    }
}

extern "C" void kernel_launch(void* const* d_in, const int* in_sizes, int n_in,
                              void* d_out, int out_size, void* d_ws, size_t ws_size,
                              hipStream_t stream) {
    const float* main_in = (const float*)d_in[0];  // [32,256,56,56]
    const float* emb_in  = (const float*)d_in[1];  // [32,512,14,14]
    const float* conv_w  = (const float*)d_in[2];  // [256,512]
    // d_in[3] = conv_b : provably dead (shift-invariant under min-max norm)
    const float* weight  = (const float*)d_in[4];  // scalar

    float* ws   = (float*)d_ws;
    float4* out = (float4*)d_out;

    k_mask_small<<<dim3(32, 8),   256, 0, stream>>>(emb_in, conv_w, ws);
    k_upsample  <<<32,            256, 0, stream>>>(weight, ws);
    k_final     <<<dim3(196, 32), 256, 0, stream>>>((const float4*)main_in, ws, out);
}